// Round 8
// baseline (144.427 us; speedup 1.0000x reference)
//
#include <hip/hip_runtime.h>
#include <math.h>

// (B,P,V,F,H) = (32,512,32,16,64). Round 12: ZERO-LDS transposed chain.
// v5-v11 invariant at ~46 us against: occupancy, spill, VMEM volume, L1/I$,
// VALU count, skew+bank-fix. The one never-ablated structural element: the
// LDS round-trip on the serial chain (MFMA -> epi -> ds_write -> ~150cy ->
// ds_read -> next MFMA, x4 per bp + pool turnarounds). This version removes
// LDS ENTIRELY via operand swap: compute h^T = mfma(A=W, B=h^T): D lane =
// v-row, acc = feature — exactly the lane layout the next layer's B-operand
// needs. Inter-layer exchange is in-register: pkrtz pack -> packed lrelu ->
// 8 shfl_xor(32)+cndmask per layer (B[s][a] = P[s>>1][2(s&1)+hb'][a&1] from
// half a>>1, derived + double-checked). Pool = per-lane mask-add (adm) +
// 5-step shfl_xor pk_max reduce over the 32 vrow lanes of each half. Bias
// via MFMA C-operand (scalar loads + hb-cndmask). W is now the A-operand;
// A-frag lane layout == B-frag layout, so prep_pack is BYTE-IDENTICAL to
// v10/v11's (those passed => both operand mappings validated on-HW).
// No __syncthreads, no LDS allocation, DS pipe carries only conflict-free
// swizzles. 1 bp/wave. MFMA 32x32x16_f16:
//   A[m=l&31][k=8*(l>>5)+j], B[k=8*(l>>5)+j][n=l&31],
//   D[row=(r&3)+8*(r>>2)+4*(l>>5)][col=l&31].
namespace {

typedef _Float16 f16x8 __attribute__((ext_vector_type(8)));
typedef _Float16 f16x2 __attribute__((ext_vector_type(2)));
typedef float    f32x16 __attribute__((ext_vector_type(16)));
typedef unsigned int uint;

__device__ __forceinline__ uint pkrtz(float a, float b) {
    return __builtin_bit_cast(uint, __builtin_amdgcn_cvt_pkrtz(a, b));
}
__device__ __forceinline__ uint pk_add(uint a, uint b) {
    uint r; asm("v_pk_add_f16 %0, %1, %2" : "=v"(r) : "v"(a), "v"(b)); return r;
}
__device__ __forceinline__ uint pk_mul(uint a, uint b) {
    uint r; asm("v_pk_mul_f16 %0, %1, %2" : "=v"(r) : "v"(a), "v"(b)); return r;
}
__device__ __forceinline__ uint pk_max(uint a, uint b) {
    uint r; asm("v_pk_max_f16 %0, %1, %2" : "=v"(r) : "v"(a), "v"(b)); return r;
}

// ---- prep: identical packing to v10/v11 (HW-validated) ----
// frag f: 0..1 = W1 (ki=0, nt2=f); 2..17 = W2 (ki=(f-2)>>1, nt2=(f-2)&1);
// 18..33 = W3. Lane l of frag f holds W[32*nt2 + (l&31)][16ki + 8*(l>>5)+j].
__global__ void prep_pack(const float* __restrict__ W1, const float* __restrict__ W2,
                          const float* __restrict__ W3, const int* __restrict__ M,
                          unsigned short* __restrict__ wsW, uint* __restrict__ wsM)
{
    int t = blockIdx.x * blockDim.x + threadIdx.x;
    if (t < 34 * 64) {
        int f = t >> 6, l = t & 63, nb = l & 31, kg = l >> 5;
        const float* src; int K, ki, nt2;
        if (f < 2)       { src = W1; K = 16;  ki = 0;           nt2 = f; }
        else if (f < 18) { int g = f - 2;  src = W2; K = 128; ki = g >> 1; nt2 = g & 1; }
        else             { int g = f - 18; src = W3; K = 128; ki = g >> 1; nt2 = g & 1; }
        const float* s = src + (size_t)(32 * nt2 + nb) * K + 16 * ki + 8 * kg;
        uint4 q;
        q.x = pkrtz(s[0], s[1]); q.y = pkrtz(s[2], s[3]);
        q.z = pkrtz(s[4], s[5]); q.w = pkrtz(s[6], s[7]);
        *(uint4*)(wsW + (size_t)f * 512 + l * 8) = q;
    } else if (t < 34 * 64 + 16384) {
        int bp = t - 34 * 64;
        const int4* mp = (const int4*)(M + bp * 32);
        uint bits = 0;
        #pragma unroll
        for (int i = 0; i < 8; ++i) {
            int4 v = mp[i];
            bits |= ((v.x ? 1u : 0u) | (v.y ? 2u : 0u) |
                     (v.z ? 4u : 0u) | (v.w ? 8u : 0u)) << (4 * i);
        }
        wsM[bp] = bits;
    }
}

__global__ __launch_bounds__(256, 3) void fused_mlp_v12(
    const float* __restrict__ X, const uint* __restrict__ MPK,
    const unsigned short* __restrict__ WF,
    const float* __restrict__ B1, const float* __restrict__ B2,
    const float* __restrict__ B3, float* __restrict__ OUT)
{
    const int t = threadIdx.x, w = t >> 6, l = t & 63;
    const int vr = l & 31, hb = l >> 5;
    const size_t bp = (size_t)blockIdx.x * 4 + w;   // one bp per wave

    const uint SL2 = pkrtz(0.01f, 0.01f);

    // per-lane pool mask: lane == vrow now, so one addend covers everything
    const uint mk = MPK[bp];
    const bool anyv = (mk != 0u);
    const uint adm = ((mk >> vr) & 1u) ? 0u : 0xFC00FC00u;   // 2x f16 -inf

    // ---- X as B-frag: B[k=8hb+j][n=vr] = X[bp][vr][8hb+j] ----
    f16x8 bfx;
    {
        const float4* xp = (const float4*)(X + ((size_t)bp * 32 + vr) * 16 + 8 * hb);
        float4 x0 = xp[0], x1 = xp[1];
        uint4 q;
        q.x = pkrtz(x0.x, x0.y); q.y = pkrtz(x0.z, x0.w);
        q.z = pkrtz(x1.x, x1.y); q.w = pkrtz(x1.z, x1.w);
        bfx = __builtin_bit_cast(f16x8, q);
    }

    // bias as MFMA C-operand: c[r] = Bp[(r&3)+8*(r>>2)+4hb+32n2]
    auto buildC = [&](const float* __restrict__ Bp, int n2) -> f32x16 {
        f32x16 cc;
        #pragma unroll
        for (int r = 0; r < 16; ++r) {
            int base = (r & 3) + 8 * (r >> 2) + 32 * n2;
            cc[r] = hb ? Bp[base + 4] : Bp[base];
        }
        return cc;
    };

    // masked cross-lane max over the 32 vrow-lanes of each half
    auto red5 = [&](uint v) -> uint {
        v = pk_max(v, (uint)__shfl_xor((int)v, 1));
        v = pk_max(v, (uint)__shfl_xor((int)v, 2));
        v = pk_max(v, (uint)__shfl_xor((int)v, 4));
        v = pk_max(v, (uint)__shfl_xor((int)v, 8));
        v = pk_max(v, (uint)__shfl_xor((int)v, 16));
        return v;
    };

    f32x16 acc0, acc1;
    uint P[2][4][2];    // packed h:    P[n2][g][b] = feats (8g+4hb+2b, +1)
    uint PL[2][4][2];   // packed pool: same feature layout, all-lanes valid

    // pack + lrelu + masked pool-reduce (acc -> P, PL)
    auto epilogue = [&]() {
        #pragma unroll
        for (int n2 = 0; n2 < 2; ++n2) {
            #pragma unroll
            for (int g = 0; g < 4; ++g)
                #pragma unroll
                for (int b = 0; b < 2; ++b) {
                    const f32x16& A = n2 ? acc1 : acc0;
                    uint d = pkrtz(A[4 * g + 2 * b], A[4 * g + 2 * b + 1]);
                    d = pk_max(d, pk_mul(d, SL2));        // packed lrelu
                    P[n2][g][b] = d;
                    uint m = red5(pk_add(d, adm));
                    PL[n2][g][b] = anyv ? m : 0u;
                }
        }
    };

    // K=128 layer: s=0..3 from P (out half), s=4..7 from PL (rep half).
    // B[s][a] = S[s>>1 (or (s-4)>>1)][2*(s&1)+hb'][a&1] taken from half a>>1.
    auto layerK = [&](int fb, const float* __restrict__ Bp) {
        f32x16 cb0 = buildC(Bp, 0), cb1 = buildC(Bp, 1);
        f32x16 a0, a1;
        #pragma unroll
        for (int s = 0; s < 8; ++s) {
            const uint (&S)[2][4][2] = (s < 4) ? P : PL;
            const int p = s & 3, n2s = p >> 1, sg = p & 1;
            uint s00 = S[n2s][2 * sg + 0][0], s01 = S[n2s][2 * sg + 0][1];
            uint s10 = S[n2s][2 * sg + 1][0], s11 = S[n2s][2 * sg + 1][1];
            uint w0 = (uint)__shfl_xor((int)s00, 32);
            uint w1 = (uint)__shfl_xor((int)s01, 32);
            uint w2 = (uint)__shfl_xor((int)s10, 32);
            uint w3 = (uint)__shfl_xor((int)s11, 32);
            uint4 q;
            q.x = hb ? w2 : s00;    // B[s][0]
            q.y = hb ? w3 : s01;    // B[s][1]
            q.z = hb ? s10 : w0;    // B[s][2]
            q.w = hb ? s11 : w1;    // B[s][3]
            f16x8 bf = __builtin_bit_cast(f16x8, q);
            const _Float16* wp = (const _Float16*)WF + (size_t)(fb + 2 * s) * 512 + l * 8;
            f16x8 wA0 = *(const f16x8*)wp;
            f16x8 wA1 = *(const f16x8*)(wp + 512);
            a0 = __builtin_amdgcn_mfma_f32_32x32x16_f16(wA0, bf, s ? a0 : cb0, 0, 0, 0);
            a1 = __builtin_amdgcn_mfma_f32_32x32x16_f16(wA1, bf, s ? a1 : cb1, 0, 0, 0);
        }
        acc0 = a0; acc1 = a1;
    };

    // ---- layer 1 (K=16, single step; W1 = frags 0,1 as A-operand) ----
    {
        const _Float16* wp = (const _Float16*)WF + l * 8;
        f16x8 wA0 = *(const f16x8*)wp;
        f16x8 wA1 = *(const f16x8*)(wp + 512);
        f32x16 cb0 = buildC(B1, 0), cb1 = buildC(B1, 1);
        acc0 = __builtin_amdgcn_mfma_f32_32x32x16_f16(wA0, bfx, cb0, 0, 0, 0);
        acc1 = __builtin_amdgcn_mfma_f32_32x32x16_f16(wA1, bfx, cb1, 0, 0, 0);
    }

    epilogue();          // h1 -> P, PL
    layerK(2, B2);       // layer 2
    epilogue();          // h2 -> P, PL
    layerK(18, B3);      // layer 3
    epilogue();          // h3 -> PL (final pools)

    // ---- final output = pool3; one writer lane per half ----
    if (vr == 0) {
        float* o = OUT + bp * 64 + 4 * hb;
        #pragma unroll
        for (int n2 = 0; n2 < 2; ++n2)
            #pragma unroll
            for (int g = 0; g < 4; ++g)
                #pragma unroll
                for (int b = 0; b < 2; ++b) {
                    f16x2 h2 = __builtin_bit_cast(f16x2, PL[n2][g][b]);
                    float2 st; st.x = (float)h2[0]; st.y = (float)h2[1];
                    *(float2*)(o + 32 * n2 + 8 * g + 2 * b) = st;
                }
    }
}
} // namespace

extern "C" void kernel_launch(void* const* d_in, const int* in_sizes, int n_in,
                              void* d_out, int out_size, void* d_ws, size_t ws_size,
                              hipStream_t stream) {
    (void)in_sizes; (void)n_in; (void)ws_size; (void)out_size;
    const float* X  = (const float*)d_in[0];
    const int*   M  = (const int*)d_in[1];
    const float* W1 = (const float*)d_in[2];
    const float* B1 = (const float*)d_in[3];
    const float* W2 = (const float*)d_in[4];
    const float* B2 = (const float*)d_in[5];
    const float* W3 = (const float*)d_in[6];
    const float* B3 = (const float*)d_in[7];
    float* OUT = (float*)d_out;

    unsigned short* WF  = (unsigned short*)d_ws;              // 34816 B
    uint*           MPK = (uint*)((char*)d_ws + 34816);       // 65536 B

    prep_pack<<<(34 * 64 + 16384 + 255) / 256, 256, 0, stream>>>(W1, W2, W3, M, WF, MPK);
    // 4096 blocks x 4 waves; ONE bp per wave, zero LDS
    fused_mlp_v12<<<4096, 256, 0, stream>>>(X, MPK, WF, B1, B2, B3, OUT);
}